// Round 1
// baseline (1140.954 us; speedup 1.0000x reference)
//
#include <hip/hip_runtime.h>
#include <math.h>

#define BB 4
#define NN1 4096
#define NN2 1024
#define DS 128
#define DD 64
#define DOUT 256
#define M1 16384        // BB*NN1
#define MH 262144       // M1*16
#define KCAT 192        // DS+DD
#define KI 8            // interp k
#define KN 16           // neighbor k

#define OUT_P1 49152                 // p1 floats
#define OUT_X  49152                 // x starts here
#define OUT_O1 4243456               // 49152 + 16384*256

// ---- workspace layout (float offsets) ----
static const size_t OFF_HPRE = 0;                      // 33,554,432  (MH*DS)
static const size_t OFF_TMP  = 33554432;               // 2,097,152  (dense pre-BN, later agg)
static const size_t OFF_XD   = OFF_TMP  + 2097152;     // x1_dense
static const size_t OFF_XI   = OFF_XD   + 2097152;     // x2_interp
static const size_t OFF_Q    = OFF_XI   + 2097152;
static const size_t OFF_K    = OFF_Q    + 2097152;
static const size_t OFF_V    = OFF_K    + 2097152;
static const size_t OFF_OUTP = OFF_V    + 2097152;     // 4,194,304 (out pre-BN)
static const size_t OFF_NIDX = OFF_OUTP + 4194304;     // 262,144 ints
static const size_t OFF_STAT = OFF_NIDX + 262144;      // 3*1024 floats

// ---------------------------------------------------------------- copy p1/o1
__global__ void k_copyout(const float* __restrict__ p1, const int* __restrict__ o1,
                          float* __restrict__ out)
{
    int i = blockIdx.x * 256 + threadIdx.x;
    if (i < OUT_P1) out[i] = p1[i];
    else if (i < OUT_P1 + BB) out[OUT_O1 + (i - OUT_P1)] = (float)o1[i - OUT_P1];
}

// ---------------------------------------------------------------- generic GEMM
// C[M,N] = Amat @ W + bias.  mode 0: plain A (stride K).
// mode 1: A row r = q[r>>4] - kmat[nidx[r]] + xe[nidx[r]]   (K==DS)
// mode 2: A row r = concat(Amat[r,0:DS], aux_q[r,0:DD])     (K==KCAT)
__global__ __launch_bounds__(256) void k_gemm(
    const float* __restrict__ Amat, const float* __restrict__ W,
    const float* __restrict__ bias, float* __restrict__ C,
    int M, int N, int K, int mode,
    const float* __restrict__ aux_q, const float* __restrict__ aux_k,
    const float* __restrict__ aux_xe, const int* __restrict__ aux_nidx)
{
    __shared__ float As[16][68];   // [k][row], +4 pad: conflict-free, 16B-aligned rows
    __shared__ float Bs[16][64];
    const int t  = threadIdx.x;
    const int tx = t & 15, ty = t >> 4;
    const int row0 = blockIdx.x * 64;
    const int col0 = blockIdx.y * 64;
    const int ar  = t >> 4;      // A-load row base
    const int akk = t & 15;      // A-load k
    const int bkk = t >> 6;      // B-load k base
    const int bc  = t & 63;      // B-load col
    float acc[4][4] = {{0.f,0.f,0.f,0.f},{0.f,0.f,0.f,0.f},
                       {0.f,0.f,0.f,0.f},{0.f,0.f,0.f,0.f}};
    for (int k0 = 0; k0 < K; k0 += 16) {
        #pragma unroll
        for (int i = 0; i < 4; i++) {
            int r  = row0 + ar + 16*i;
            int kk = k0 + akk;
            float v;
            if (mode == 0) {
                v = Amat[(size_t)r * K + kk];
            } else if (mode == 1) {
                int m  = aux_nidx[r];
                int pr = r >> 4;
                v = aux_q[(size_t)pr*DS + kk] - aux_k[(size_t)m*DS + kk]
                    + aux_xe[(size_t)m*DS + kk];
            } else {
                v = (kk < DS) ? Amat[(size_t)r*DS + kk]
                              : aux_q[(size_t)r*DD + (kk - DS)];
            }
            As[akk][ar + 16*i] = v;
        }
        #pragma unroll
        for (int i = 0; i < 4; i++)
            Bs[bkk + 4*i][bc] = W[(size_t)(k0 + bkk + 4*i) * N + col0 + bc];
        __syncthreads();
        #pragma unroll
        for (int kk = 0; kk < 16; kk++) {
            float a4[4], b4[4];
            #pragma unroll
            for (int i = 0; i < 4; i++) a4[i] = As[kk][ty*4 + i];
            #pragma unroll
            for (int j = 0; j < 4; j++) b4[j] = Bs[kk][tx*4 + j];
            #pragma unroll
            for (int i = 0; i < 4; i++)
                #pragma unroll
                for (int j = 0; j < 4; j++)
                    acc[i][j] = fmaf(a4[i], b4[j], acc[i][j]);
        }
        __syncthreads();
    }
    #pragma unroll
    for (int i = 0; i < 4; i++) {
        int r = row0 + ty*4 + i;
        #pragma unroll
        for (int j = 0; j < 4; j++) {
            int c = col0 + tx*4 + j;
            float v = acc[i][j];
            if (bias) v += bias[c];
            C[(size_t)r*N + c] = v;
        }
    }
}

// ---------------------------------------------------------------- column stats
__global__ __launch_bounds__(256) void k_colstats(
    const float* __restrict__ X, int M, int N,
    float* __restrict__ sums, float* __restrict__ sumsq)
{
    __shared__ float sh[256], sh2[256];
    int t = threadIdx.x;
    int c = t & (N - 1);          // N is 128 or 256
    int rl = t / N;
    int stride = 256 / N;
    int rowsPerBlk = (M + gridDim.x - 1) / gridDim.x;
    int r0 = blockIdx.x * rowsPerBlk;
    int r1 = min(M, r0 + rowsPerBlk);
    float s = 0.f, ss = 0.f;
    for (int r = r0 + rl; r < r1; r += stride) {
        float v = X[(size_t)r*N + c];
        s += v; ss += v*v;
    }
    sh[t] = s; sh2[t] = ss;
    __syncthreads();
    if (t < N) {
        for (int i = 1; i < stride; i++) { s += sh[t + i*N]; ss += sh2[t + i*N]; }
        atomicAdd(&sums[c], s);
        atomicAdd(&sumsq[c], ss);
    }
}

__global__ void k_finalize(const float* __restrict__ sums, const float* __restrict__ sumsq,
                           const float* __restrict__ g, const float* __restrict__ bt,
                           int M, int N, float* __restrict__ scale, float* __restrict__ shift)
{
    int c = blockIdx.x * blockDim.x + threadIdx.x;
    if (c < N) {
        float m  = sums[c] / (float)M;
        float var = sumsq[c] / (float)M - m*m;
        float sc = g[c] * rsqrtf(var + 1e-5f);
        scale[c] = sc;
        shift[c] = bt[c] - m * sc;
    }
}

__global__ __launch_bounds__(256) void k_bnrelu(
    const float* __restrict__ X, const float* __restrict__ scale,
    const float* __restrict__ shift, float* __restrict__ Y, size_t total, int N)
{
    size_t i = (size_t)blockIdx.x * 256 + threadIdx.x;
    if (i < total) {
        int c = (int)(i & (size_t)(N - 1));
        Y[i] = fmaxf(fmaf(X[i], scale[c], shift[c]), 0.f);
    }
}

// ---------------------------------------------------------------- interpolation
__global__ __launch_bounds__(64) void k_interp(
    const float* __restrict__ p1, const float* __restrict__ p2,
    const float* __restrict__ x2, float* __restrict__ xi)
{
    int gp = blockIdx.x;
    int b  = gp >> 12;
    int lane = threadIdx.x;
    float px = p1[gp*3+0], py = p1[gp*3+1], pz = p1[gp*3+2];
    float sa = px*px + py*py + pz*pz;
    float d8[KI]; int i8[KI];
    #pragma unroll
    for (int i = 0; i < KI; i++) { d8[i] = INFINITY; i8[i] = -1; }
    const float* p2b = p2 + (size_t)b*NN2*3;
    for (int tt = 0; tt < NN2/64; tt++) {
        int j = lane + 64*tt;
        float qx = p2b[j*3+0], qy = p2b[j*3+1], qz = p2b[j*3+2];
        float sb  = qx*qx + qy*qy + qz*qz;
        float dot = px*qx + py*qy + pz*qz;
        float d = sqrtf(fmaxf((sa + sb) - 2.f*dot, 0.f));
        if (d < d8[KI-1]) {                 // strict: equal dist keeps lower idx
            d8[KI-1] = d; i8[KI-1] = j;
            #pragma unroll
            for (int s = KI-1; s > 0; s--) {
                if (d8[s] < d8[s-1]) {
                    float td = d8[s]; d8[s] = d8[s-1]; d8[s-1] = td;
                    int   ti = i8[s]; i8[s] = i8[s-1]; i8[s-1] = ti;
                }
            }
        }
    }
    __shared__ float sd[KI*64];
    __shared__ int   si[KI*64];
    __shared__ float seld[KI];
    __shared__ int   seli[KI];
    #pragma unroll
    for (int i = 0; i < KI; i++) { sd[i*64+lane] = d8[i]; si[i*64+lane] = i8[i]; }
    for (int r = 0; r < KI; r++) {
        __syncthreads();
        float bd = INFINITY; int bi = 0x7fffffff; int bslot = 0;
        #pragma unroll
        for (int i = 0; i < KI; i++) {
            float dv = sd[i*64+lane]; int iv = si[i*64+lane];
            if (dv < bd || (dv == bd && iv < bi)) { bd = dv; bi = iv; bslot = i; }
        }
        int blane = lane;
        for (int off = 32; off; off >>= 1) {
            float od = __shfl_xor(bd, off);
            int   oi = __shfl_xor(bi, off);
            int   ol = __shfl_xor(blane, off);
            int   osl= __shfl_xor(bslot, off);
            if (od < bd || (od == bd && oi < bi)) { bd = od; bi = oi; blane = ol; bslot = osl; }
        }
        if (lane == 0) { seld[r] = bd; seli[r] = bi; sd[bslot*64 + blane] = INFINITY; }
    }
    __syncthreads();
    float w[KI]; float wsum = 0.f;
    #pragma unroll
    for (int r = 0; r < KI; r++) { w[r] = 1.f / (seld[r] + 1e-8f); wsum += w[r]; }
    float inv = 1.f / wsum;
    const float* x2b = x2 + (size_t)b*NN2*DS;
    float a0 = 0.f, a1 = 0.f;
    #pragma unroll
    for (int r = 0; r < KI; r++) {
        float wr = w[r] * inv;
        const float* row = x2b + (size_t)seli[r]*DS;
        a0 = fmaf(wr, row[lane],      a0);
        a1 = fmaf(wr, row[lane + 64], a1);
    }
    xi[(size_t)gp*DS + lane]      = a0;
    xi[(size_t)gp*DS + lane + 64] = a1;
}

// ---------------------------------------------------------------- kNN-16 (self)
__global__ __launch_bounds__(64) void k_knn(
    const float* __restrict__ p1, int* __restrict__ nidx)
{
    int gp = blockIdx.x;
    int b  = gp >> 12;
    int lane = threadIdx.x;
    float px = p1[gp*3+0], py = p1[gp*3+1], pz = p1[gp*3+2];
    float sa = px*px + py*py + pz*pz;
    float dk[KN]; int ik[KN];
    #pragma unroll
    for (int i = 0; i < KN; i++) { dk[i] = INFINITY; ik[i] = -1; }
    const float* pb = p1 + (size_t)b*NN1*3;
    for (int tt = 0; tt < NN1/64; tt++) {
        int j = lane + 64*tt;
        float qx = pb[j*3+0], qy = pb[j*3+1], qz = pb[j*3+2];
        float sb  = qx*qx + qy*qy + qz*qz;
        float dot = px*qx + py*qy + pz*qz;
        float d = sqrtf(fmaxf((sa + sb) - 2.f*dot, 0.f));
        if (d < dk[KN-1]) {
            dk[KN-1] = d; ik[KN-1] = j;
            #pragma unroll
            for (int s = KN-1; s > 0; s--) {
                if (dk[s] < dk[s-1]) {
                    float td = dk[s]; dk[s] = dk[s-1]; dk[s-1] = td;
                    int   ti = ik[s]; ik[s] = ik[s-1]; ik[s-1] = ti;
                }
            }
        }
    }
    __shared__ float sd[KN*64];
    __shared__ int   si[KN*64];
    #pragma unroll
    for (int i = 0; i < KN; i++) { sd[i*64+lane] = dk[i]; si[i*64+lane] = ik[i]; }
    for (int r = 0; r < KN; r++) {
        __syncthreads();
        float bd = INFINITY; int bi = 0x7fffffff; int bslot = 0;
        #pragma unroll
        for (int i = 0; i < KN; i++) {
            float dv = sd[i*64+lane]; int iv = si[i*64+lane];
            if (dv < bd || (dv == bd && iv < bi)) { bd = dv; bi = iv; bslot = i; }
        }
        int blane = lane;
        for (int off = 32; off; off >>= 1) {
            float od = __shfl_xor(bd, off);
            int   oi = __shfl_xor(bi, off);
            int   ol = __shfl_xor(blane, off);
            int   osl= __shfl_xor(bslot, off);
            if (od < bd || (od == bd && oi < bi)) { bd = od; bi = oi; blane = ol; bslot = osl; }
        }
        if (lane == 0) { nidx[gp*KN + r] = b*NN1 + bi; sd[bslot*64 + blane] = INFINITY; }
    }
}

// ----------------------------------------------- fused sim GEMM + softmax + agg
__global__ __launch_bounds__(256) void k_attn(
    const float* __restrict__ hpre, const float* __restrict__ scale_h,
    const float* __restrict__ shift_h, const float* __restrict__ W2,
    const float* __restrict__ b2, const float* __restrict__ v,
    const float* __restrict__ xe, const int* __restrict__ nidx,
    float* __restrict__ agg)
{
    __shared__ float Ah[16][132];
    __shared__ float Ws[16][128];
    __shared__ float sim[16][132];
    int gp = blockIdx.x;
    int t  = threadIdx.x;
    #pragma unroll
    for (int i = 0; i < 8; i++) {
        int e = t + 256*i;
        int j = e >> 7, c = e & 127;
        float vv = hpre[((size_t)gp*16 + j)*DS + c];
        Ah[j][c] = fmaxf(fmaf(vv, scale_h[c], shift_h[c]), 0.f);
    }
    int j  = t >> 4;
    int cb = t & 15;
    float acc[8];
    #pragma unroll
    for (int u = 0; u < 8; u++) acc[u] = b2[cb + 16*u];
    for (int k0 = 0; k0 < DS; k0 += 16) {
        __syncthreads();
        #pragma unroll
        for (int i = 0; i < 8; i++) {
            int e = t + 256*i;
            int kk = e >> 7, c = e & 127;
            Ws[kk][c] = W2[(size_t)(k0 + kk)*DS + c];
        }
        __syncthreads();
        #pragma unroll
        for (int kk = 0; kk < 16; kk++) {
            float a = Ah[j][k0 + kk];
            #pragma unroll
            for (int u = 0; u < 8; u++)
                acc[u] = fmaf(a, Ws[kk][cb + 16*u], acc[u]);
        }
    }
    __syncthreads();
    #pragma unroll
    for (int u = 0; u < 8; u++) sim[j][cb + 16*u] = acc[u];
    __syncthreads();
    if (t < DS) {
        int c = t;
        float mx = -INFINITY;
        #pragma unroll
        for (int jj = 0; jj < 16; jj++) mx = fmaxf(mx, sim[jj][c]);
        float e16[16]; float s = 0.f;
        #pragma unroll
        for (int jj = 0; jj < 16; jj++) { e16[jj] = expf(sim[jj][c] - mx); s += e16[jj]; }
        float invs = 1.f / s;
        float a = 0.f;
        #pragma unroll
        for (int jj = 0; jj < 16; jj++) {
            int m = nidx[gp*16 + jj];
            a = fmaf(e16[jj]*invs, v[(size_t)m*DS + c] + xe[(size_t)m*DS + c], a);
        }
        agg[(size_t)gp*DS + c] = a;
    }
}

// ---------------------------------------------------------------- launch
extern "C" void kernel_launch(void* const* d_in, const int* in_sizes, int n_in,
                              void* d_out, int out_size, void* d_ws, size_t ws_size,
                              hipStream_t stream)
{
    const float* p1 = (const float*)d_in[0];
    const float* x1 = (const float*)d_in[1];
    const int*   o1 = (const int*)d_in[2];
    const float* p2 = (const float*)d_in[3];
    const float* x2 = (const float*)d_in[4];
    const float* W_dense = (const float*)d_in[7];
    const float* b_dense = (const float*)d_in[8];
    const float* g_dense = (const float*)d_in[9];
    const float* bt_dense= (const float*)d_in[10];
    const float* Wq = (const float*)d_in[11];
    const float* Wk = (const float*)d_in[12];
    const float* Wv = (const float*)d_in[13];
    const float* W1 = (const float*)d_in[14];
    const float* b1 = (const float*)d_in[15];
    const float* g1 = (const float*)d_in[16];
    const float* bt1= (const float*)d_in[17];
    const float* W2 = (const float*)d_in[18];
    const float* b2 = (const float*)d_in[19];
    const float* W_out = (const float*)d_in[20];
    const float* b_out = (const float*)d_in[21];
    const float* g_out = (const float*)d_in[22];
    const float* bt_out= (const float*)d_in[23];

    float* ws   = (float*)d_ws;
    float* hpre = ws + OFF_HPRE;
    float* tmp  = ws + OFF_TMP;     // dense pre-BN, then agg
    float* xd   = ws + OFF_XD;
    float* xi   = ws + OFF_XI;
    float* qm   = ws + OFF_Q;
    float* km   = ws + OFF_K;
    float* vm   = ws + OFF_V;
    float* outp = ws + OFF_OUTP;
    int*   nidx = (int*)(ws + OFF_NIDX);
    float* stat = ws + OFF_STAT;
    float* sums_d = stat,        *sumsq_d = stat+256,  *scale_d = stat+512,  *shift_d = stat+768;
    float* sums_h = stat+1024,   *sumsq_h = stat+1280, *scale_h = stat+1536, *shift_h = stat+1792;
    float* sums_o = stat+2048,   *sumsq_o = stat+2304, *scale_o = stat+2560, *shift_o = stat+2816;
    float* out = (float*)d_out;

    hipMemsetAsync(stat, 0, 3*1024*sizeof(float), stream);
    k_copyout<<<(OUT_P1 + BB + 255)/256, 256, 0, stream>>>(p1, o1, out);

    // dense_mlp: x1 @ W_dense + b_dense -> BN stats -> relu(bn) -> xd
    k_gemm<<<dim3(M1/64, DS/64), 256, 0, stream>>>(x1, W_dense, b_dense, tmp,
        M1, DS, DD, 0, nullptr, nullptr, nullptr, nullptr);
    k_colstats<<<128, 256, 0, stream>>>(tmp, M1, DS, sums_d, sumsq_d);
    k_finalize<<<1, 256, 0, stream>>>(sums_d, sumsq_d, g_dense, bt_dense, M1, DS, scale_d, shift_d);
    k_bnrelu<<<(M1*DS)/256, 256, 0, stream>>>(tmp, scale_d, shift_d, xd, (size_t)M1*DS, DS);

    // inverse-distance kNN interpolation -> xi
    k_interp<<<M1, 64, 0, stream>>>(p1, p2, x2, xi);

    // q, k, v projections
    k_gemm<<<dim3(M1/64, DS/64), 256, 0, stream>>>(xd, Wq, nullptr, qm,
        M1, DS, DS, 0, nullptr, nullptr, nullptr, nullptr);
    k_gemm<<<dim3(M1/64, DS/64), 256, 0, stream>>>(xi, Wk, nullptr, km,
        M1, DS, DS, 0, nullptr, nullptr, nullptr, nullptr);
    k_gemm<<<dim3(M1/64, DS/64), 256, 0, stream>>>(xi, Wv, nullptr, vm,
        M1, DS, DS, 0, nullptr, nullptr, nullptr, nullptr);

    // 16-NN of p1 within each batch
    k_knn<<<M1, 64, 0, stream>>>(p1, nidx);

    // h = (q - k[n] + xe[n]) @ W1 + b1   (rows built on the fly), then BN stats
    k_gemm<<<dim3(MH/64, DS/64), 256, 0, stream>>>(nullptr, W1, b1, hpre,
        MH, DS, DS, 1, qm, km, xd, nidx);
    k_colstats<<<1024, 256, 0, stream>>>(hpre, MH, DS, sums_h, sumsq_h);
    k_finalize<<<1, 256, 0, stream>>>(sums_h, sumsq_h, g1, bt1, MH, DS, scale_h, shift_h);

    // sim = relu(bn(h)) @ W2 + b2 ; softmax over 16 neighbors ; agg
    k_attn<<<M1, 256, 0, stream>>>(hpre, scale_h, shift_h, W2, b2, vm, xd, nidx, tmp);

    // out = relu(bn(concat(agg, x1) @ W_out + b_out))
    k_gemm<<<dim3(M1/64, DOUT/64), 256, 0, stream>>>(tmp, W_out, b_out, outp,
        M1, DOUT, KCAT, 2, x1, nullptr, nullptr, nullptr);
    k_colstats<<<128, 256, 0, stream>>>(outp, M1, DOUT, sums_o, sumsq_o);
    k_finalize<<<1, 256, 0, stream>>>(sums_o, sumsq_o, g_out, bt_out, M1, DOUT, scale_o, shift_o);
    k_bnrelu<<<(M1*DOUT)/256, 256, 0, stream>>>(outp, scale_o, shift_o, out + OUT_X,
        (size_t)M1*DOUT, DOUT);
}

// Round 2
// 721.501 us; speedup vs baseline: 1.5814x; 1.5814x over previous
//
#include <hip/hip_runtime.h>
#include <math.h>

#define BB 4
#define NN1 4096
#define NN2 1024
#define DS 128
#define DD 64
#define DOUT 256
#define M1 16384        // BB*NN1
#define MH 262144       // M1*16
#define KCAT 192        // DS+DD
#define KI 8            // interp k
#define KN 16           // neighbor k

#define OUT_P1 49152
#define OUT_X  49152
#define OUT_O1 4243456

// ---- workspace layout (float offsets) ----
static const size_t OFF_HPRE = 0;                      // bf16 MH*DS = 16,777,216 floats worth
static const size_t OFF_W1SW = 16777216;               // 8192 floats (16384 bf16)
static const size_t OFF_W2SW = 16785408;               // 8192 floats
static const size_t OFF_TMP  = 33554432;               // dense pre-BN, later agg
static const size_t OFF_XD   = OFF_TMP  + 2097152;
static const size_t OFF_XI   = OFF_XD   + 2097152;
static const size_t OFF_Q    = OFF_XI   + 2097152;
static const size_t OFF_K    = OFF_Q    + 2097152;
static const size_t OFF_V    = OFF_K    + 2097152;
static const size_t OFF_OUTP = OFF_V    + 2097152;
static const size_t OFF_NIDX = OFF_OUTP + 4194304;
static const size_t OFF_STAT = OFF_NIDX + 262144;

typedef __attribute__((ext_vector_type(8))) short short8;
typedef __attribute__((ext_vector_type(4))) float floatx4;

__device__ inline unsigned short f2bf(float f) {
    union { float f; unsigned int u; } x; x.f = f;
    unsigned int r = x.u + 0x7fffu + ((x.u >> 16) & 1u);
    return (unsigned short)(r >> 16);
}
__device__ inline float bf2f(unsigned short h) {
    union { unsigned int u; float f; } x; x.u = ((unsigned int)h) << 16;
    return x.f;
}

// ---------------------------------------------------------------- copy p1/o1
__global__ void k_copyout(const float* __restrict__ p1, const int* __restrict__ o1,
                          float* __restrict__ out)
{
    int i = blockIdx.x * 256 + threadIdx.x;
    if (i < OUT_P1) out[i] = p1[i];
    else if (i < OUT_P1 + BB) out[OUT_O1 + (i - OUT_P1)] = (float)o1[i - OUT_P1];
}

// ------------------------------------------------- W swizzle to fragment order
// Wsw[t*8 + j] = bf16(W[k][n]) with t = ks*512 + cj*64 + lane,
// n = cj*16 + (lane&15), k = ks*32 + (lane>>4)*8 + j
__global__ __launch_bounds__(256) void k_swizzle(const float* __restrict__ W,
                                                 unsigned short* __restrict__ Wsw)
{
    int t = blockIdx.x * 256 + threadIdx.x;    // 0..2047
    int ks   = t >> 9;
    int cj   = (t >> 6) & 7;
    int lane = t & 63;
    int n  = cj * 16 + (lane & 15);
    int k0 = ks * 32 + (lane >> 4) * 8;
    unsigned int o[8];
    #pragma unroll
    for (int j = 0; j < 8; j++) o[j] = f2bf(W[(size_t)(k0 + j) * 128 + n]);
    uint4 pk;
    pk.x = o[0] | (o[1] << 16);
    pk.y = o[2] | (o[3] << 16);
    pk.z = o[4] | (o[5] << 16);
    pk.w = o[6] | (o[7] << 16);
    ((uint4*)Wsw)[t] = pk;
}

// ---------------------------------------------------------------- fp32 GEMM
// mode 0: plain A (stride K).  mode 2: A row r = concat(Amat[r,0:DS], aux[r,0:DD])
__global__ __launch_bounds__(256) void k_gemm(
    const float* __restrict__ Amat, const float* __restrict__ W,
    const float* __restrict__ bias, float* __restrict__ C,
    int M, int N, int K, int mode, const float* __restrict__ aux)
{
    __shared__ float As[16][68];
    __shared__ float Bs[16][64];
    const int t  = threadIdx.x;
    const int tx = t & 15, ty = t >> 4;
    const int row0 = blockIdx.x * 64;
    const int col0 = blockIdx.y * 64;
    const int ar  = t >> 4;
    const int akk = t & 15;
    const int bkk = t >> 6;
    const int bc  = t & 63;
    float acc[4][4] = {{0.f,0.f,0.f,0.f},{0.f,0.f,0.f,0.f},
                       {0.f,0.f,0.f,0.f},{0.f,0.f,0.f,0.f}};
    for (int k0 = 0; k0 < K; k0 += 16) {
        #pragma unroll
        for (int i = 0; i < 4; i++) {
            int r  = row0 + ar + 16*i;
            int kk = k0 + akk;
            float v;
            if (mode == 0) v = Amat[(size_t)r * K + kk];
            else v = (kk < DS) ? Amat[(size_t)r*DS + kk] : aux[(size_t)r*DD + (kk - DS)];
            As[akk][ar + 16*i] = v;
        }
        #pragma unroll
        for (int i = 0; i < 4; i++)
            Bs[bkk + 4*i][bc] = W[(size_t)(k0 + bkk + 4*i) * N + col0 + bc];
        __syncthreads();
        #pragma unroll
        for (int kk = 0; kk < 16; kk++) {
            float a4[4], b4[4];
            #pragma unroll
            for (int i = 0; i < 4; i++) a4[i] = As[kk][ty*4 + i];
            #pragma unroll
            for (int j = 0; j < 4; j++) b4[j] = Bs[kk][tx*4 + j];
            #pragma unroll
            for (int i = 0; i < 4; i++)
                #pragma unroll
                for (int j = 0; j < 4; j++)
                    acc[i][j] = fmaf(a4[i], b4[j], acc[i][j]);
        }
        __syncthreads();
    }
    #pragma unroll
    for (int i = 0; i < 4; i++) {
        int r = row0 + ty*4 + i;
        #pragma unroll
        for (int j = 0; j < 4; j++) {
            int c = col0 + tx*4 + j;
            float v = acc[i][j];
            if (bias) v += bias[c];
            C[(size_t)r*N + c] = v;
        }
    }
}

// ------------------------------------------- MFMA h-GEMM + fused BN stats
// hpre[r][n] = b1[n] + sum_k (q[r>>4][k] - km[nidx[r]][k] + xe[nidx[r]][k]) * W1[k][n]
__global__ __launch_bounds__(256) void k_gemm_h(
    const float* __restrict__ q, const float* __restrict__ km,
    const float* __restrict__ xe, const int* __restrict__ nidx,
    const unsigned short* __restrict__ W1sw, const float* __restrict__ b1,
    unsigned short* __restrict__ hpre,
    float* __restrict__ sums, float* __restrict__ sumsq)
{
    __shared__ unsigned short WF[16384];
    __shared__ unsigned short outT[128*128];
    __shared__ float sstat[256];
    const int t = threadIdx.x;
    const int w = t >> 6, lane = t & 63;
    sstat[t] = 0.f;
    #pragma unroll
    for (int i = 0; i < 8; i++)
        ((uint4*)WF)[t + 256*i] = ((const uint4*)W1sw)[t + 256*i];
    __syncthreads();

    const int quad = lane >> 4, c = lane & 15;
    const int r0 = blockIdx.x * 128 + w * 32;
    const int nid0 = nidx[r0 + c];
    const int nid1 = nidx[r0 + 16 + c];
    const int pr0 = r0 >> 4;
    const int pr1 = pr0 + 1;

    floatx4 acc[2][8];
    #pragma unroll
    for (int ti = 0; ti < 2; ti++)
        #pragma unroll
        for (int cj = 0; cj < 8; cj++)
            acc[ti][cj] = (floatx4){0.f, 0.f, 0.f, 0.f};

    for (int ks = 0; ks < 4; ks++) {
        short8 bf[8];
        #pragma unroll
        for (int cj = 0; cj < 8; cj++)
            bf[cj] = ((const short8*)WF)[(ks*8 + cj)*64 + lane];
        const int ko = ks*32 + quad*8;
        #pragma unroll
        for (int ti = 0; ti < 2; ti++) {
            const int pr = ti ? pr1 : pr0;
            const int m  = ti ? nid1 : nid0;
            const float* qp = q  + (size_t)pr*DS + ko;
            const float* kp = km + (size_t)m*DS + ko;
            const float* xp = xe + (size_t)m*DS + ko;
            floatx4 qa = *(const floatx4*)qp,       qb = *(const floatx4*)(qp+4);
            floatx4 ka = *(const floatx4*)kp,       kb = *(const floatx4*)(kp+4);
            floatx4 xa = *(const floatx4*)xp,       xb = *(const floatx4*)(xp+4);
            short8 af;
            #pragma unroll
            for (int j = 0; j < 4; j++) af[j]   = (short)f2bf(qa[j] - ka[j] + xa[j]);
            #pragma unroll
            for (int j = 0; j < 4; j++) af[4+j] = (short)f2bf(qb[j] - kb[j] + xb[j]);
            #pragma unroll
            for (int cj = 0; cj < 8; cj++)
                acc[ti][cj] = __builtin_amdgcn_mfma_f32_16x16x32_bf16(af, bf[cj], acc[ti][cj], 0, 0, 0);
        }
    }

    // bias + stats + LDS repack
    #pragma unroll
    for (int cj = 0; cj < 8; cj++) {
        const float bb = b1[cj*16 + c];
        float s = 0.f, ss = 0.f;
        #pragma unroll
        for (int ti = 0; ti < 2; ti++)
            #pragma unroll
            for (int p = 0; p < 4; p++) {
                float v = acc[ti][cj][p] + bb;
                s += v; ss += v*v;
                int lr = w*32 + ti*16 + quad*4 + p;
                outT[lr*128 + cj*16 + c] = f2bf(v);
            }
        s  += __shfl_xor(s, 16);  s  += __shfl_xor(s, 32);
        ss += __shfl_xor(ss, 16); ss += __shfl_xor(ss, 32);
        if (quad == 0) {
            atomicAdd(&sstat[cj*16 + c], s);
            atomicAdd(&sstat[128 + cj*16 + c], ss);
        }
    }
    __syncthreads();
    unsigned short* gdst = hpre + (size_t)blockIdx.x * 128 * 128;
    #pragma unroll
    for (int i = 0; i < 8; i++)
        ((uint4*)gdst)[t + 256*i] = ((const uint4*)outT)[t + 256*i];
    if (t < 128) atomicAdd(&sums[t], sstat[t]);
    else         atomicAdd(&sumsq[t - 128], sstat[t]);
}

// ---------------------------- MFMA attn: bn+relu -> sim GEMM -> softmax -> agg
__global__ __launch_bounds__(256) void k_attn2(
    const unsigned short* __restrict__ hpre, const float* __restrict__ scale_h,
    const float* __restrict__ shift_h, const unsigned short* __restrict__ W2sw,
    const float* __restrict__ v, const float* __restrict__ xe,
    const int* __restrict__ nidx, float* __restrict__ agg)
{
    __shared__ unsigned short WF[16384];
    const int t = threadIdx.x;
    #pragma unroll
    for (int i = 0; i < 8; i++)
        ((uint4*)WF)[t + 256*i] = ((const uint4*)W2sw)[t + 256*i];
    __syncthreads();

    const int w = t >> 6, lane = t & 63;
    const int gp = blockIdx.x * 4 + w;
    const int quad = lane >> 4, c = lane & 15;

    floatx4 acc[8];
    #pragma unroll
    for (int cj = 0; cj < 8; cj++) acc[cj] = (floatx4){0.f, 0.f, 0.f, 0.f};

    for (int ks = 0; ks < 4; ks++) {
        const int ko = ks*32 + quad*8;
        const unsigned short* hp = hpre + ((size_t)gp*16 + c)*DS + ko;
        uint4 hv = *(const uint4*)hp;
        floatx4 sc0 = *(const floatx4*)(scale_h + ko);
        floatx4 sc1 = *(const floatx4*)(scale_h + ko + 4);
        floatx4 sh0 = *(const floatx4*)(shift_h + ko);
        floatx4 sh1 = *(const floatx4*)(shift_h + ko + 4);
        unsigned int hw[4] = {hv.x, hv.y, hv.z, hv.w};
        short8 af;
        #pragma unroll
        for (int j = 0; j < 4; j++) {
            unsigned short u0 = (unsigned short)(hw[j] & 0xffffu);
            unsigned short u1 = (unsigned short)(hw[j] >> 16);
            float f0 = fmaxf(fmaf(bf2f(u0), (j<2)?sc0[2*j]:sc1[2*j-4],   (j<2)?sh0[2*j]:sh1[2*j-4]),   0.f);
            float f1 = fmaxf(fmaf(bf2f(u1), (j<2)?sc0[2*j+1]:sc1[2*j-3], (j<2)?sh0[2*j+1]:sh1[2*j-3]), 0.f);
            af[2*j]   = (short)f2bf(f0);
            af[2*j+1] = (short)f2bf(f1);
        }
        #pragma unroll
        for (int cj = 0; cj < 8; cj++) {
            short8 bfv = ((const short8*)WF)[(ks*8 + cj)*64 + lane];
            acc[cj] = __builtin_amdgcn_mfma_f32_16x16x32_bf16(af, bfv, acc[cj], 0, 0, 0);
        }
    }

    int nid[4];
    #pragma unroll
    for (int p = 0; p < 4; p++) nid[p] = nidx[gp*16 + quad*4 + p];

    #pragma unroll
    for (int cj = 0; cj < 8; cj++) {
        float m4 = fmaxf(fmaxf(acc[cj][0], acc[cj][1]), fmaxf(acc[cj][2], acc[cj][3]));
        m4 = fmaxf(m4, __shfl_xor(m4, 16));
        m4 = fmaxf(m4, __shfl_xor(m4, 32));
        float e[4]; float s4 = 0.f;
        #pragma unroll
        for (int p = 0; p < 4; p++) { e[p] = __expf(acc[cj][p] - m4); s4 += e[p]; }
        s4 += __shfl_xor(s4, 16); s4 += __shfl_xor(s4, 32);
        const float inv = 1.f / s4;
        const int col = cj*16 + c;
        float a = 0.f;
        #pragma unroll
        for (int p = 0; p < 4; p++) {
            const int m = nid[p];
            a = fmaf(e[p]*inv, v[(size_t)m*DS + col] + xe[(size_t)m*DS + col], a);
        }
        a += __shfl_xor(a, 16); a += __shfl_xor(a, 32);
        if (quad == 0) agg[(size_t)gp*DS + col] = a;
    }
}

// ---------------------------------------------------------------- column stats
__global__ __launch_bounds__(256) void k_colstats(
    const float* __restrict__ X, int M, int N,
    float* __restrict__ sums, float* __restrict__ sumsq)
{
    __shared__ float sh[256], sh2[256];
    int t = threadIdx.x;
    int c = t & (N - 1);
    int rl = t / N;
    int stride = 256 / N;
    int rowsPerBlk = (M + gridDim.x - 1) / gridDim.x;
    int r0 = blockIdx.x * rowsPerBlk;
    int r1 = min(M, r0 + rowsPerBlk);
    float s = 0.f, ss = 0.f;
    for (int r = r0 + rl; r < r1; r += stride) {
        float v = X[(size_t)r*N + c];
        s += v; ss += v*v;
    }
    sh[t] = s; sh2[t] = ss;
    __syncthreads();
    if (t < N) {
        for (int i = 1; i < stride; i++) { s += sh[t + i*N]; ss += sh2[t + i*N]; }
        atomicAdd(&sums[c], s);
        atomicAdd(&sumsq[c], ss);
    }
}

__global__ void k_finalize(const float* __restrict__ sums, const float* __restrict__ sumsq,
                           const float* __restrict__ g, const float* __restrict__ bt,
                           int M, int N, float* __restrict__ scale, float* __restrict__ shift)
{
    int c = blockIdx.x * blockDim.x + threadIdx.x;
    if (c < N) {
        float m  = sums[c] / (float)M;
        float var = sumsq[c] / (float)M - m*m;
        float sc = g[c] * rsqrtf(var + 1e-5f);
        scale[c] = sc;
        shift[c] = bt[c] - m * sc;
    }
}

__global__ __launch_bounds__(256) void k_bnrelu(
    const float* __restrict__ X, const float* __restrict__ scale,
    const float* __restrict__ shift, float* __restrict__ Y, size_t total, int N)
{
    size_t i = (size_t)blockIdx.x * 256 + threadIdx.x;
    if (i < total) {
        int c = (int)(i & (size_t)(N - 1));
        Y[i] = fmaxf(fmaf(X[i], scale[c], shift[c]), 0.f);
    }
}

// ---------------------------------------------------------------- interpolation
__global__ __launch_bounds__(64) void k_interp(
    const float* __restrict__ p1, const float* __restrict__ p2,
    const float* __restrict__ x2, float* __restrict__ xi)
{
    int gp = blockIdx.x;
    int b  = gp >> 12;
    int lane = threadIdx.x;
    float px = p1[gp*3+0], py = p1[gp*3+1], pz = p1[gp*3+2];
    float sa = px*px + py*py + pz*pz;
    float d8[KI]; int i8[KI];
    #pragma unroll
    for (int i = 0; i < KI; i++) { d8[i] = INFINITY; i8[i] = -1; }
    const float* p2b = p2 + (size_t)b*NN2*3;
    for (int tt = 0; tt < NN2/64; tt++) {
        int j = lane + 64*tt;
        float qx = p2b[j*3+0], qy = p2b[j*3+1], qz = p2b[j*3+2];
        float sb  = qx*qx + qy*qy + qz*qz;
        float dot = px*qx + py*qy + pz*qz;
        float d = sqrtf(fmaxf((sa + sb) - 2.f*dot, 0.f));
        if (d < d8[KI-1]) {
            d8[KI-1] = d; i8[KI-1] = j;
            #pragma unroll
            for (int s = KI-1; s > 0; s--) {
                if (d8[s] < d8[s-1]) {
                    float td = d8[s]; d8[s] = d8[s-1]; d8[s-1] = td;
                    int   ti = i8[s]; i8[s] = i8[s-1]; i8[s-1] = ti;
                }
            }
        }
    }
    __shared__ float sd[KI*64];
    __shared__ int   si[KI*64];
    __shared__ float seld[KI];
    __shared__ int   seli[KI];
    #pragma unroll
    for (int i = 0; i < KI; i++) { sd[i*64+lane] = d8[i]; si[i*64+lane] = i8[i]; }
    for (int r = 0; r < KI; r++) {
        __syncthreads();
        float bd = INFINITY; int bi = 0x7fffffff; int bslot = 0;
        #pragma unroll
        for (int i = 0; i < KI; i++) {
            float dv = sd[i*64+lane]; int iv = si[i*64+lane];
            if (dv < bd || (dv == bd && iv < bi)) { bd = dv; bi = iv; bslot = i; }
        }
        int blane = lane;
        for (int off = 32; off; off >>= 1) {
            float od = __shfl_xor(bd, off);
            int   oi = __shfl_xor(bi, off);
            int   ol = __shfl_xor(blane, off);
            int   osl= __shfl_xor(bslot, off);
            if (od < bd || (od == bd && oi < bi)) { bd = od; bi = oi; blane = ol; bslot = osl; }
        }
        if (lane == 0) { seld[r] = bd; seli[r] = bi; sd[bslot*64 + blane] = INFINITY; }
    }
    __syncthreads();
    float w[KI]; float wsum = 0.f;
    #pragma unroll
    for (int r = 0; r < KI; r++) { w[r] = 1.f / (seld[r] + 1e-8f); wsum += w[r]; }
    float inv = 1.f / wsum;
    const float* x2b = x2 + (size_t)b*NN2*DS;
    float a0 = 0.f, a1 = 0.f;
    #pragma unroll
    for (int r = 0; r < KI; r++) {
        float wr = w[r] * inv;
        const float* row = x2b + (size_t)seli[r]*DS;
        a0 = fmaf(wr, row[lane],      a0);
        a1 = fmaf(wr, row[lane + 64], a1);
    }
    xi[(size_t)gp*DS + lane]      = a0;
    xi[(size_t)gp*DS + lane + 64] = a1;
}

// ---------------------------------------------------------------- kNN-16 (self)
__global__ __launch_bounds__(64) void k_knn(
    const float* __restrict__ p1, int* __restrict__ nidx)
{
    int gp = blockIdx.x;
    int b  = gp >> 12;
    int lane = threadIdx.x;
    float px = p1[gp*3+0], py = p1[gp*3+1], pz = p1[gp*3+2];
    float sa = px*px + py*py + pz*pz;
    float dk[KN]; int ik[KN];
    #pragma unroll
    for (int i = 0; i < KN; i++) { dk[i] = INFINITY; ik[i] = -1; }
    const float* pb = p1 + (size_t)b*NN1*3;
    for (int tt = 0; tt < NN1/64; tt++) {
        int j = lane + 64*tt;
        float qx = pb[j*3+0], qy = pb[j*3+1], qz = pb[j*3+2];
        float sb  = qx*qx + qy*qy + qz*qz;
        float dot = px*qx + py*qy + pz*qz;
        float d = sqrtf(fmaxf((sa + sb) - 2.f*dot, 0.f));
        if (d < dk[KN-1]) {
            dk[KN-1] = d; ik[KN-1] = j;
            #pragma unroll
            for (int s = KN-1; s > 0; s--) {
                if (dk[s] < dk[s-1]) {
                    float td = dk[s]; dk[s] = dk[s-1]; dk[s-1] = td;
                    int   ti = ik[s]; ik[s] = ik[s-1]; ik[s-1] = ti;
                }
            }
        }
    }
    __shared__ float sd[KN*64];
    __shared__ int   si[KN*64];
    #pragma unroll
    for (int i = 0; i < KN; i++) { sd[i*64+lane] = dk[i]; si[i*64+lane] = ik[i]; }
    for (int r = 0; r < KN; r++) {
        __syncthreads();
        float bd = INFINITY; int bi = 0x7fffffff; int bslot = 0;
        #pragma unroll
        for (int i = 0; i < KN; i++) {
            float dv = sd[i*64+lane]; int iv = si[i*64+lane];
            if (dv < bd || (dv == bd && iv < bi)) { bd = dv; bi = iv; bslot = i; }
        }
        int blane = lane;
        for (int off = 32; off; off >>= 1) {
            float od = __shfl_xor(bd, off);
            int   oi = __shfl_xor(bi, off);
            int   ol = __shfl_xor(blane, off);
            int   osl= __shfl_xor(bslot, off);
            if (od < bd || (od == bd && oi < bi)) { bd = od; bi = oi; blane = ol; bslot = osl; }
        }
        if (lane == 0) { nidx[gp*KN + r] = b*NN1 + bi; sd[bslot*64 + blane] = INFINITY; }
    }
}

// ---------------------------------------------------------------- launch
extern "C" void kernel_launch(void* const* d_in, const int* in_sizes, int n_in,
                              void* d_out, int out_size, void* d_ws, size_t ws_size,
                              hipStream_t stream)
{
    const float* p1 = (const float*)d_in[0];
    const float* x1 = (const float*)d_in[1];
    const int*   o1 = (const int*)d_in[2];
    const float* p2 = (const float*)d_in[3];
    const float* x2 = (const float*)d_in[4];
    const float* W_dense = (const float*)d_in[7];
    const float* b_dense = (const float*)d_in[8];
    const float* g_dense = (const float*)d_in[9];
    const float* bt_dense= (const float*)d_in[10];
    const float* Wq = (const float*)d_in[11];
    const float* Wk = (const float*)d_in[12];
    const float* Wv = (const float*)d_in[13];
    const float* W1 = (const float*)d_in[14];
    const float* b1 = (const float*)d_in[15];
    const float* g1 = (const float*)d_in[16];
    const float* bt1= (const float*)d_in[17];
    const float* W2 = (const float*)d_in[18];
    const float* W_out = (const float*)d_in[20];
    const float* b_out = (const float*)d_in[21];
    const float* g_out = (const float*)d_in[22];
    const float* bt_out= (const float*)d_in[23];

    float* ws   = (float*)d_ws;
    unsigned short* hpre = (unsigned short*)(ws + OFF_HPRE);
    unsigned short* W1sw = (unsigned short*)(ws + OFF_W1SW);
    unsigned short* W2sw = (unsigned short*)(ws + OFF_W2SW);
    float* tmp  = ws + OFF_TMP;
    float* xd   = ws + OFF_XD;
    float* xi   = ws + OFF_XI;
    float* qm   = ws + OFF_Q;
    float* km   = ws + OFF_K;
    float* vm   = ws + OFF_V;
    float* outp = ws + OFF_OUTP;
    int*   nidx = (int*)(ws + OFF_NIDX);
    float* stat = ws + OFF_STAT;
    float* sums_d = stat,      *sumsq_d = stat+256,  *scale_d = stat+512,  *shift_d = stat+768;
    float* sums_h = stat+1024, *sumsq_h = stat+1280, *scale_h = stat+1536, *shift_h = stat+1792;
    float* sums_o = stat+2048, *sumsq_o = stat+2304, *scale_o = stat+2560, *shift_o = stat+2816;
    float* out = (float*)d_out;

    hipMemsetAsync(stat, 0, 3*1024*sizeof(float), stream);
    k_copyout<<<(OUT_P1 + BB + 255)/256, 256, 0, stream>>>(p1, o1, out);
    k_swizzle<<<8, 256, 0, stream>>>(W1, W1sw);
    k_swizzle<<<8, 256, 0, stream>>>(W2, W2sw);

    // dense_mlp
    k_gemm<<<dim3(M1/64, DS/64), 256, 0, stream>>>(x1, W_dense, b_dense, tmp,
        M1, DS, DD, 0, nullptr);
    k_colstats<<<128, 256, 0, stream>>>(tmp, M1, DS, sums_d, sumsq_d);
    k_finalize<<<1, 256, 0, stream>>>(sums_d, sumsq_d, g_dense, bt_dense, M1, DS, scale_d, shift_d);
    k_bnrelu<<<(M1*DS)/256, 256, 0, stream>>>(tmp, scale_d, shift_d, xd, (size_t)M1*DS, DS);

    // interpolation
    k_interp<<<M1, 64, 0, stream>>>(p1, p2, x2, xi);

    // q, k, v projections
    k_gemm<<<dim3(M1/64, DS/64), 256, 0, stream>>>(xd, Wq, nullptr, qm, M1, DS, DS, 0, nullptr);
    k_gemm<<<dim3(M1/64, DS/64), 256, 0, stream>>>(xi, Wk, nullptr, km, M1, DS, DS, 0, nullptr);
    k_gemm<<<dim3(M1/64, DS/64), 256, 0, stream>>>(xi, Wv, nullptr, vm, M1, DS, DS, 0, nullptr);

    // kNN
    k_knn<<<M1, 64, 0, stream>>>(p1, nidx);

    // h-GEMM (MFMA, fused BN stats) -> hpre bf16
    k_gemm_h<<<MH/128, 256, 0, stream>>>(qm, km, xd, nidx, W1sw, b1, hpre, sums_h, sumsq_h);
    k_finalize<<<1, 256, 0, stream>>>(sums_h, sumsq_h, g1, bt1, MH, DS, scale_h, shift_h);

    // attn (MFMA)
    k_attn2<<<M1/4, 256, 0, stream>>>(hpre, scale_h, shift_h, W2sw, vm, xd, nidx, tmp);

    // output mlp
    k_gemm<<<dim3(M1/64, DOUT/64), 256, 0, stream>>>(tmp, W_out, b_out, outp,
        M1, DOUT, KCAT, 2, x1);
    k_colstats<<<128, 256, 0, stream>>>(outp, M1, DOUT, sums_o, sumsq_o);
    k_finalize<<<1, 256, 0, stream>>>(sums_o, sumsq_o, g_out, bt_out, M1, DOUT, scale_o, shift_o);
    k_bnrelu<<<(M1*DOUT)/256, 256, 0, stream>>>(outp, scale_o, shift_o, out + OUT_X,
        (size_t)M1*DOUT, DOUT);
}

// Round 3
// 645.144 us; speedup vs baseline: 1.7685x; 1.1184x over previous
//
#include <hip/hip_runtime.h>
#include <math.h>

#define BB 4
#define NN1 4096
#define NN2 1024
#define DS 128
#define DD 64
#define DOUT 256
#define M1 16384        // BB*NN1
#define MH 262144       // M1*16
#define KCAT 192        // DS+DD
#define KI 8            // interp k
#define KN 16           // neighbor k

#define OUT_P1 49152
#define OUT_X  49152
#define OUT_O1 4243456

// ---- workspace layout (float offsets) ----
static const size_t OFF_HPRE = 0;                      // bf16 MH*DS = 16,777,216 floats worth
static const size_t OFF_WTS  = 16777216;               // swizzled weights (hi/lo), 278528 ushorts
static const size_t OFF_TMP  = 33554432;               // dense pre-BN, later agg
static const size_t OFF_XD   = OFF_TMP  + 2097152;
static const size_t OFF_XI   = OFF_XD   + 2097152;
static const size_t OFF_Q    = OFF_XI   + 2097152;
static const size_t OFF_K    = OFF_Q    + 2097152;
static const size_t OFF_V    = OFF_K    + 2097152;
static const size_t OFF_OUTP = OFF_V    + 2097152;
static const size_t OFF_NIDX = OFF_OUTP + 4194304;
static const size_t OFF_STAT = OFF_NIDX + 262144;

// ushort offsets inside the weights region
#define WDH 0
#define WDL 8192
#define WQH 16384
#define WQL 32768
#define WKH 49152
#define WKL 65536
#define WVH 81920
#define WVL 98304
#define W1H 114688
#define W1L 131072
#define W2H 147456
#define W2L 163840
#define WOH 180224
#define WOL 229376

typedef __attribute__((ext_vector_type(8))) short short8;
typedef __attribute__((ext_vector_type(4))) float floatx4;

__device__ inline unsigned short f2bf(float f) {
    union { float f; unsigned int u; } x; x.f = f;
    unsigned int r = x.u + 0x7fffu + ((x.u >> 16) & 1u);
    return (unsigned short)(r >> 16);
}
__device__ inline float bf2f(unsigned short h) {
    union { unsigned int u; float f; } x; x.u = ((unsigned int)h) << 16;
    return x.f;
}
__device__ inline unsigned long long shfl_xor_u64(unsigned long long v, int m) {
    unsigned lo = (unsigned)v, hi = (unsigned)(v >> 32);
    lo = (unsigned)__shfl_xor((int)lo, m);
    hi = (unsigned)__shfl_xor((int)hi, m);
    return ((unsigned long long)hi << 32) | lo;
}

// ---------------------------------------------------------------- copy p1/o1
__global__ void k_copyout(const float* __restrict__ p1, const int* __restrict__ o1,
                          float* __restrict__ out)
{
    int i = blockIdx.x * 256 + threadIdx.x;
    if (i < OUT_P1) out[i] = p1[i];
    else if (i < OUT_P1 + BB) out[OUT_O1 + (i - OUT_P1)] = (float)o1[i - OUT_P1];
}

// --------------------------------------- W swizzle to frag order, hi+lo planes
// layout: uint4 index fid*64+lane, fid = slab*(N/16)+cj;
// element j: k = slab*32+(lane>>4)*8+j, n = cj*16+(lane&15)
__global__ __launch_bounds__(64) void k_swizzle_hl(const float* __restrict__ W,
                                                   int N, unsigned short* __restrict__ hi,
                                                   unsigned short* __restrict__ lo)
{
    int fid = blockIdx.x, lane = threadIdx.x;
    int ncj = N >> 4;
    int slab = fid / ncj, cj = fid - slab*ncj;
    int n  = cj*16 + (lane & 15);
    int k0 = slab*32 + (lane >> 4)*8;
    unsigned int oh[8], ol[8];
    #pragma unroll
    for (int j = 0; j < 8; j++) {
        float v = W[(size_t)(k0 + j) * N + n];
        unsigned short h = f2bf(v);
        oh[j] = h;
        ol[j] = f2bf(v - bf2f(h));
    }
    uint4 ph, pl;
    ph.x = oh[0] | (oh[1] << 16); ph.y = oh[2] | (oh[3] << 16);
    ph.z = oh[4] | (oh[5] << 16); ph.w = oh[6] | (oh[7] << 16);
    pl.x = ol[0] | (ol[1] << 16); pl.y = ol[2] | (ol[3] << 16);
    pl.z = ol[4] | (ol[5] << 16); pl.w = ol[6] | (ol[7] << 16);
    ((uint4*)hi)[fid*64 + lane] = ph;
    ((uint4*)lo)[fid*64 + lane] = pl;
}

// ----------------------------- split-bf16 MFMA GEMM (near-fp32 via hi/lo x 3)
// mode 0: A plain (stride K). mode 2: A = concat(Amat[.,0:128], aux[.,0:64])
template<int N, int K, int MODE>
__global__ __launch_bounds__(256) void k_gemm_mf(
    const float* __restrict__ Amat, const unsigned short* __restrict__ Whi,
    const unsigned short* __restrict__ Wlo, const float* __restrict__ bias,
    float* __restrict__ C, const float* __restrict__ aux)
{
    const int t = threadIdx.x, w = t >> 6, lane = t & 63;
    const int quad = lane >> 4, c = lane & 15;
    const int row = blockIdx.x*64 + w*16 + c;
    const int sA = (MODE == 2) ? DS : K;
    constexpr int nslab = K >> 5;
    constexpr int ncj = N >> 4;
    floatx4 acc[ncj];
    #pragma unroll
    for (int cj = 0; cj < ncj; cj++) acc[cj] = (floatx4){0.f,0.f,0.f,0.f};

    #pragma unroll
    for (int slab = 0; slab < nslab; slab++) {
        const int kk = slab*32 + quad*8;
        const float* src;
        if (MODE == 2 && kk >= DS) src = aux + (size_t)row*DD + (kk - DS);
        else                       src = Amat + (size_t)row*sA + kk;
        floatx4 va = *(const floatx4*)src;
        floatx4 vb = *(const floatx4*)(src + 4);
        short8 ahi, alo;
        #pragma unroll
        for (int j = 0; j < 4; j++) {
            unsigned short h = f2bf(va[j]);
            ahi[j] = (short)h; alo[j] = (short)f2bf(va[j] - bf2f(h));
        }
        #pragma unroll
        for (int j = 0; j < 4; j++) {
            unsigned short h = f2bf(vb[j]);
            ahi[4+j] = (short)h; alo[4+j] = (short)f2bf(vb[j] - bf2f(h));
        }
        const short8* bh = (const short8*)Whi + (size_t)slab*ncj*64;
        const short8* bl = (const short8*)Wlo + (size_t)slab*ncj*64;
        #pragma unroll
        for (int cj = 0; cj < ncj; cj++) {
            short8 bhv = bh[cj*64 + lane];
            short8 blv = bl[cj*64 + lane];
            acc[cj] = __builtin_amdgcn_mfma_f32_16x16x32_bf16(alo, bhv, acc[cj], 0, 0, 0);
            acc[cj] = __builtin_amdgcn_mfma_f32_16x16x32_bf16(ahi, blv, acc[cj], 0, 0, 0);
            acc[cj] = __builtin_amdgcn_mfma_f32_16x16x32_bf16(ahi, bhv, acc[cj], 0, 0, 0);
        }
    }
    const int rbase = blockIdx.x*64 + w*16 + quad*4;
    #pragma unroll
    for (int cj = 0; cj < ncj; cj++) {
        const float bb = bias ? bias[cj*16 + c] : 0.f;
        #pragma unroll
        for (int p = 0; p < 4; p++)
            C[(size_t)(rbase + p)*N + cj*16 + c] = acc[cj][p] + bb;
    }
}

// ------------------------------------------- MFMA h-GEMM + fused BN stats
__global__ __launch_bounds__(256) void k_gemm_h(
    const float* __restrict__ q, const float* __restrict__ km,
    const float* __restrict__ xe, const int* __restrict__ nidx,
    const unsigned short* __restrict__ W1sw, const float* __restrict__ b1,
    unsigned short* __restrict__ hpre,
    float* __restrict__ sums, float* __restrict__ sumsq)
{
    __shared__ unsigned short WF[16384];
    __shared__ unsigned short outT[128*128];
    __shared__ float sstat[256];
    const int t = threadIdx.x;
    const int w = t >> 6, lane = t & 63;
    sstat[t] = 0.f;
    #pragma unroll
    for (int i = 0; i < 8; i++)
        ((uint4*)WF)[t + 256*i] = ((const uint4*)W1sw)[t + 256*i];
    __syncthreads();

    const int quad = lane >> 4, c = lane & 15;
    const int r0 = blockIdx.x * 128 + w * 32;
    const int nid0 = nidx[r0 + c];
    const int nid1 = nidx[r0 + 16 + c];
    const int pr0 = r0 >> 4;
    const int pr1 = pr0 + 1;

    floatx4 acc[2][8];
    #pragma unroll
    for (int ti = 0; ti < 2; ti++)
        #pragma unroll
        for (int cj = 0; cj < 8; cj++)
            acc[ti][cj] = (floatx4){0.f, 0.f, 0.f, 0.f};

    for (int ks = 0; ks < 4; ks++) {
        short8 bf[8];
        #pragma unroll
        for (int cj = 0; cj < 8; cj++)
            bf[cj] = ((const short8*)WF)[(ks*8 + cj)*64 + lane];
        const int ko = ks*32 + quad*8;
        #pragma unroll
        for (int ti = 0; ti < 2; ti++) {
            const int pr = ti ? pr1 : pr0;
            const int m  = ti ? nid1 : nid0;
            const float* qp = q  + (size_t)pr*DS + ko;
            const float* kp = km + (size_t)m*DS + ko;
            const float* xp = xe + (size_t)m*DS + ko;
            floatx4 qa = *(const floatx4*)qp,       qb = *(const floatx4*)(qp+4);
            floatx4 ka = *(const floatx4*)kp,       kb = *(const floatx4*)(kp+4);
            floatx4 xa = *(const floatx4*)xp,       xb = *(const floatx4*)(xp+4);
            short8 af;
            #pragma unroll
            for (int j = 0; j < 4; j++) af[j]   = (short)f2bf(qa[j] - ka[j] + xa[j]);
            #pragma unroll
            for (int j = 0; j < 4; j++) af[4+j] = (short)f2bf(qb[j] - kb[j] + xb[j]);
            #pragma unroll
            for (int cj = 0; cj < 8; cj++)
                acc[ti][cj] = __builtin_amdgcn_mfma_f32_16x16x32_bf16(af, bf[cj], acc[ti][cj], 0, 0, 0);
        }
    }

    #pragma unroll
    for (int cj = 0; cj < 8; cj++) {
        const float bb = b1[cj*16 + c];
        float s = 0.f, ss = 0.f;
        #pragma unroll
        for (int ti = 0; ti < 2; ti++)
            #pragma unroll
            for (int p = 0; p < 4; p++) {
                float v = acc[ti][cj][p] + bb;
                s += v; ss += v*v;
                int lr = w*32 + ti*16 + quad*4 + p;
                outT[lr*128 + cj*16 + c] = f2bf(v);
            }
        s  += __shfl_xor(s, 16);  s  += __shfl_xor(s, 32);
        ss += __shfl_xor(ss, 16); ss += __shfl_xor(ss, 32);
        if (quad == 0) {
            atomicAdd(&sstat[cj*16 + c], s);
            atomicAdd(&sstat[128 + cj*16 + c], ss);
        }
    }
    __syncthreads();
    unsigned short* gdst = hpre + (size_t)blockIdx.x * 128 * 128;
    #pragma unroll
    for (int i = 0; i < 8; i++)
        ((uint4*)gdst)[t + 256*i] = ((const uint4*)outT)[t + 256*i];
    if (t < 128) atomicAdd(&sums[t], sstat[t]);
    else         atomicAdd(&sumsq[t - 128], sstat[t]);
}

// ---------------------------- MFMA attn: bn+relu -> sim GEMM -> softmax -> agg
__global__ __launch_bounds__(256) void k_attn2(
    const unsigned short* __restrict__ hpre, const float* __restrict__ scale_h,
    const float* __restrict__ shift_h, const unsigned short* __restrict__ W2sw,
    const float* __restrict__ v, const float* __restrict__ xe,
    const int* __restrict__ nidx, float* __restrict__ agg)
{
    __shared__ unsigned short WF[16384];
    const int t = threadIdx.x;
    #pragma unroll
    for (int i = 0; i < 8; i++)
        ((uint4*)WF)[t + 256*i] = ((const uint4*)W2sw)[t + 256*i];
    __syncthreads();

    const int w = t >> 6, lane = t & 63;
    const int gp = blockIdx.x * 4 + w;
    const int quad = lane >> 4, c = lane & 15;

    floatx4 acc[8];
    #pragma unroll
    for (int cj = 0; cj < 8; cj++) acc[cj] = (floatx4){0.f, 0.f, 0.f, 0.f};

    for (int ks = 0; ks < 4; ks++) {
        const int ko = ks*32 + quad*8;
        const unsigned short* hp = hpre + ((size_t)gp*16 + c)*DS + ko;
        uint4 hv = *(const uint4*)hp;
        floatx4 sc0 = *(const floatx4*)(scale_h + ko);
        floatx4 sc1 = *(const floatx4*)(scale_h + ko + 4);
        floatx4 sh0 = *(const floatx4*)(shift_h + ko);
        floatx4 sh1 = *(const floatx4*)(shift_h + ko + 4);
        unsigned int hw[4] = {hv.x, hv.y, hv.z, hv.w};
        short8 af;
        #pragma unroll
        for (int j = 0; j < 4; j++) {
            unsigned short u0 = (unsigned short)(hw[j] & 0xffffu);
            unsigned short u1 = (unsigned short)(hw[j] >> 16);
            float f0 = fmaxf(fmaf(bf2f(u0), (j<2)?sc0[2*j]:sc1[2*j-4],   (j<2)?sh0[2*j]:sh1[2*j-4]),   0.f);
            float f1 = fmaxf(fmaf(bf2f(u1), (j<2)?sc0[2*j+1]:sc1[2*j-3], (j<2)?sh0[2*j+1]:sh1[2*j-3]), 0.f);
            af[2*j]   = (short)f2bf(f0);
            af[2*j+1] = (short)f2bf(f1);
        }
        #pragma unroll
        for (int cj = 0; cj < 8; cj++) {
            short8 bfv = ((const short8*)WF)[(ks*8 + cj)*64 + lane];
            acc[cj] = __builtin_amdgcn_mfma_f32_16x16x32_bf16(af, bfv, acc[cj], 0, 0, 0);
        }
    }

    int nid[4];
    #pragma unroll
    for (int p = 0; p < 4; p++) nid[p] = nidx[gp*16 + quad*4 + p];

    #pragma unroll
    for (int cj = 0; cj < 8; cj++) {
        float m4 = fmaxf(fmaxf(acc[cj][0], acc[cj][1]), fmaxf(acc[cj][2], acc[cj][3]));
        m4 = fmaxf(m4, __shfl_xor(m4, 16));
        m4 = fmaxf(m4, __shfl_xor(m4, 32));
        float e[4]; float s4 = 0.f;
        #pragma unroll
        for (int p = 0; p < 4; p++) { e[p] = __expf(acc[cj][p] - m4); s4 += e[p]; }
        s4 += __shfl_xor(s4, 16); s4 += __shfl_xor(s4, 32);
        const float inv = 1.f / s4;
        const int col = cj*16 + c;
        float a = 0.f;
        #pragma unroll
        for (int p = 0; p < 4; p++) {
            const int m = nid[p];
            a = fmaf(e[p]*inv, v[(size_t)m*DS + col] + xe[(size_t)m*DS + col], a);
        }
        a += __shfl_xor(a, 16); a += __shfl_xor(a, 32);
        if (quad == 0) agg[(size_t)gp*DS + col] = a;
    }
}

// ---------------------------------------------------------------- column stats
__global__ __launch_bounds__(256) void k_colstats(
    const float* __restrict__ X, int M, int N,
    float* __restrict__ sums, float* __restrict__ sumsq)
{
    __shared__ float sh[256], sh2[256];
    int t = threadIdx.x;
    int c = t & (N - 1);
    int rl = t / N;
    int stride = 256 / N;
    int rowsPerBlk = (M + gridDim.x - 1) / gridDim.x;
    int r0 = blockIdx.x * rowsPerBlk;
    int r1 = min(M, r0 + rowsPerBlk);
    float s = 0.f, ss = 0.f;
    for (int r = r0 + rl; r < r1; r += stride) {
        float v = X[(size_t)r*N + c];
        s += v; ss += v*v;
    }
    sh[t] = s; sh2[t] = ss;
    __syncthreads();
    if (t < N) {
        for (int i = 1; i < stride; i++) { s += sh[t + i*N]; ss += sh2[t + i*N]; }
        atomicAdd(&sums[c], s);
        atomicAdd(&sumsq[c], ss);
    }
}

__global__ void k_finalize(const float* __restrict__ sums, const float* __restrict__ sumsq,
                           const float* __restrict__ g, const float* __restrict__ bt,
                           int M, int N, float* __restrict__ scale, float* __restrict__ shift)
{
    int c = blockIdx.x * blockDim.x + threadIdx.x;
    if (c < N) {
        float m  = sums[c] / (float)M;
        float var = sumsq[c] / (float)M - m*m;
        float sc = g[c] * rsqrtf(var + 1e-5f);
        scale[c] = sc;
        shift[c] = bt[c] - m * sc;
    }
}

__global__ __launch_bounds__(256) void k_bnrelu(
    const float* __restrict__ X, const float* __restrict__ scale,
    const float* __restrict__ shift, float* __restrict__ Y, size_t total, int N)
{
    size_t i = (size_t)blockIdx.x * 256 + threadIdx.x;
    if (i < total) {
        int c = (int)(i & (size_t)(N - 1));
        Y[i] = fmaxf(fmaf(X[i], scale[c], shift[c]), 0.f);
    }
}

// ---------------------------------------------------------------- interpolation
__global__ __launch_bounds__(64) void k_interp(
    const float* __restrict__ p1, const float* __restrict__ p2,
    const float* __restrict__ x2, float* __restrict__ xi)
{
    int gp = blockIdx.x;
    int b  = gp >> 12;
    int lane = threadIdx.x;
    float px = p1[gp*3+0], py = p1[gp*3+1], pz = p1[gp*3+2];
    float sa = px*px + py*py + pz*pz;
    float d8[KI]; int i8[KI];
    #pragma unroll
    for (int i = 0; i < KI; i++) { d8[i] = INFINITY; i8[i] = -1; }
    const float* p2b = p2 + (size_t)b*NN2*3;
    for (int tt = 0; tt < NN2/64; tt++) {
        int j = lane + 64*tt;
        float qx = p2b[j*3+0], qy = p2b[j*3+1], qz = p2b[j*3+2];
        float sb  = qx*qx + qy*qy + qz*qz;
        float dot = px*qx + py*qy + pz*qz;
        float d = sqrtf(fmaxf((sa + sb) - 2.f*dot, 0.f));
        if (d < d8[KI-1]) {
            d8[KI-1] = d; i8[KI-1] = j;
            #pragma unroll
            for (int s = KI-1; s > 0; s--) {
                if (d8[s] < d8[s-1]) {
                    float td = d8[s]; d8[s] = d8[s-1]; d8[s-1] = td;
                    int   ti = i8[s]; i8[s] = i8[s-1]; i8[s-1] = ti;
                }
            }
        }
    }
    __shared__ float sd[KI*64];
    __shared__ int   si[KI*64];
    __shared__ float seld[KI];
    __shared__ int   seli[KI];
    #pragma unroll
    for (int i = 0; i < KI; i++) { sd[i*64+lane] = d8[i]; si[i*64+lane] = i8[i]; }
    for (int r = 0; r < KI; r++) {
        __syncthreads();
        float bd = INFINITY; int bi = 0x7fffffff; int bslot = 0;
        #pragma unroll
        for (int i = 0; i < KI; i++) {
            float dv = sd[i*64+lane]; int iv = si[i*64+lane];
            if (dv < bd || (dv == bd && iv < bi)) { bd = dv; bi = iv; bslot = i; }
        }
        int blane = lane;
        for (int off = 32; off; off >>= 1) {
            float od = __shfl_xor(bd, off);
            int   oi = __shfl_xor(bi, off);
            int   ol = __shfl_xor(blane, off);
            int   osl= __shfl_xor(bslot, off);
            if (od < bd || (od == bd && oi < bi)) { bd = od; bi = oi; blane = ol; bslot = osl; }
        }
        if (lane == 0) { seld[r] = bd; seli[r] = bi; sd[bslot*64 + blane] = INFINITY; }
    }
    __syncthreads();
    float w[KI]; float wsum = 0.f;
    #pragma unroll
    for (int r = 0; r < KI; r++) { w[r] = 1.f / (seld[r] + 1e-8f); wsum += w[r]; }
    float inv = 1.f / wsum;
    const float* x2b = x2 + (size_t)b*NN2*DS;
    float a0 = 0.f, a1 = 0.f;
    #pragma unroll
    for (int r = 0; r < KI; r++) {
        float wr = w[r] * inv;
        const float* row = x2b + (size_t)seli[r]*DS;
        a0 = fmaf(wr, row[lane],      a0);
        a1 = fmaf(wr, row[lane + 64], a1);
    }
    xi[(size_t)gp*DS + lane]      = a0;
    xi[(size_t)gp*DS + lane + 64] = a1;
}

// ------------------------------------------------ kNN-16 via LDS radix select
__global__ __launch_bounds__(64) void k_knn_rs(
    const float* __restrict__ p1, int* __restrict__ nidx)
{
    __shared__ unsigned int keys[NN1];   // d^2 float bits (monotone, >= 0)
    __shared__ unsigned int hist[256];
    __shared__ unsigned int skey[64];
    __shared__ unsigned int sidx[64];
    const int gp = blockIdx.x, b = gp >> 12, lane = threadIdx.x;
    const float px = p1[gp*3+0], py = p1[gp*3+1], pz = p1[gp*3+2];
    const float sa = px*px + py*py + pz*pz;
    const float* pb = p1 + (size_t)b*NN1*3;

    for (int t = 0; t < NN1/64; t++) {
        int j = lane + 64*t;
        float qx = pb[j*3+0], qy = pb[j*3+1], qz = pb[j*3+2];
        float sb  = qx*qx + qy*qy + qz*qz;
        float dot = px*qx + py*qy + pz*qz;
        float d2 = fmaxf((sa + sb) - 2.f*dot, 0.f);
        keys[j] = __float_as_uint(d2);
    }
    __syncthreads();

    unsigned pfx = 0;
    int shift = 24;
    int S = 0;          // count of keys strictly below current bucket
    int cntB = 0;
    int gsh = 0;
    bool fallback = false;
    for (int round = 0; round < 4; round++) {
        ((uint4*)hist)[lane] = (uint4){0u,0u,0u,0u};
        __syncthreads();
        const unsigned pmask = (round == 0) ? 0u : (0xFFFFFFFFu << (shift + 8));
        for (int t = 0; t < NN1/64; t++) {
            unsigned key = keys[lane + 64*t];
            if ((key & pmask) == pfx)
                atomicAdd(&hist[(key >> shift) & 255], 1u);
        }
        __syncthreads();
        uint4 h4 = ((uint4*)hist)[lane];
        unsigned hv[4] = {h4.x, h4.y, h4.z, h4.w};
        unsigned s4 = hv[0] + hv[1] + hv[2] + hv[3];
        unsigned incl = s4;
        #pragma unroll
        for (int off = 1; off < 64; off <<= 1) {
            unsigned o = __shfl_up(incl, off);
            if (lane >= off) incl += o;
        }
        unsigned excl = incl - s4;
        const int need = 16 - S;
        int which = -1; unsigned below = 0;
        unsigned cum = excl;
        #pragma unroll
        for (int i = 0; i < 4; i++) {
            if (which < 0 && (int)cum < need && need <= (int)(cum + hv[i])) { which = i; below = cum; }
            cum += hv[i];
        }
        unsigned long long bal = __ballot(which >= 0);
        int src = __ffsll((unsigned long long)bal) - 1;
        int Bbin = __shfl(which, src) + src*4;
        unsigned belowB = (unsigned)__shfl((int)below, src);
        cntB = (int)hist[Bbin];
        S += (int)belowB;
        pfx |= ((unsigned)Bbin) << shift;
        if (S + cntB <= 64) { gsh = shift; break; }
        if (shift == 0)     { gsh = 0; fallback = true; break; }
        shift -= 8;
        __syncthreads();   // hist reuse next round
    }

    const unsigned long long lmask = (1ull << lane) - 1ull;
    int total;
    if (!fallback) {
        const unsigned P = pfx >> gsh;
        int cnt = 0;
        for (int t = 0; t < NN1/64; t++) {
            int j = lane + 64*t;
            unsigned key = keys[j];
            bool cflag = ((key >> gsh) <= P);
            unsigned long long bal = __ballot(cflag);
            if (cflag) {
                int pos = cnt + __popcll(bal & lmask);
                skey[pos] = key; sidx[pos] = (unsigned)j;
            }
            cnt += __popcll(bal);
        }
        total = cnt;   // == S + cntB <= 64
    } else {
        // exact-equal-key tail: definite-ins first, then members in idx order, capped
        int cnt = 0;
        for (int t = 0; t < NN1/64; t++) {
            int j = lane + 64*t;
            unsigned key = keys[j];
            bool cflag = (key < pfx);
            unsigned long long bal = __ballot(cflag);
            if (cflag) {
                int pos = cnt + __popcll(bal & lmask);
                skey[pos] = key; sidx[pos] = (unsigned)j;
            }
            cnt += __popcll(bal);
        }
        for (int t = 0; t < NN1/64; t++) {
            int j = lane + 64*t;
            unsigned key = keys[j];
            bool cflag = (key == pfx);
            unsigned long long bal = __ballot(cflag);
            if (cflag) {
                int pos = cnt + __popcll(bal & lmask);
                if (pos < 64) { skey[pos] = key; sidx[pos] = (unsigned)j; }
            }
            cnt += __popcll(bal);
        }
        total = min(cnt, 64);
    }
    __syncthreads();

    unsigned long long v = ~0ull;
    if (lane < total) v = (((unsigned long long)skey[lane]) << 32) | sidx[lane];
    // bitonic sort ascending over 64 lanes: (d2, idx) lexicographic
    #pragma unroll
    for (int k = 2; k <= 64; k <<= 1) {
        #pragma unroll
        for (int jj = k >> 1; jj > 0; jj >>= 1) {
            unsigned long long p = shfl_xor_u64(v, jj);
            bool up = ((lane & k) == 0);
            bool takeMin = (((lane & jj) == 0) == up);
            bool pl = p < v;
            v = (takeMin == pl) ? p : v;
        }
    }
    if (lane < KN)
        nidx[gp*KN + lane] = b*NN1 + (int)(v & 0xffffffffull);
}

// ---------------------------------------------------------------- launch
extern "C" void kernel_launch(void* const* d_in, const int* in_sizes, int n_in,
                              void* d_out, int out_size, void* d_ws, size_t ws_size,
                              hipStream_t stream)
{
    const float* p1 = (const float*)d_in[0];
    const float* x1 = (const float*)d_in[1];
    const int*   o1 = (const int*)d_in[2];
    const float* p2 = (const float*)d_in[3];
    const float* x2 = (const float*)d_in[4];
    const float* W_dense = (const float*)d_in[7];
    const float* b_dense = (const float*)d_in[8];
    const float* g_dense = (const float*)d_in[9];
    const float* bt_dense= (const float*)d_in[10];
    const float* Wq = (const float*)d_in[11];
    const float* Wk = (const float*)d_in[12];
    const float* Wv = (const float*)d_in[13];
    const float* W1 = (const float*)d_in[14];
    const float* b1 = (const float*)d_in[15];
    const float* g1 = (const float*)d_in[16];
    const float* bt1= (const float*)d_in[17];
    const float* W2 = (const float*)d_in[18];
    const float* W_out = (const float*)d_in[20];
    const float* b_out = (const float*)d_in[21];
    const float* g_out = (const float*)d_in[22];
    const float* bt_out= (const float*)d_in[23];

    float* ws   = (float*)d_ws;
    unsigned short* hpre = (unsigned short*)(ws + OFF_HPRE);
    unsigned short* wts  = (unsigned short*)(ws + OFF_WTS);
    float* tmp  = ws + OFF_TMP;
    float* xd   = ws + OFF_XD;
    float* xi   = ws + OFF_XI;
    float* qm   = ws + OFF_Q;
    float* km   = ws + OFF_K;
    float* vm   = ws + OFF_V;
    float* outp = ws + OFF_OUTP;
    int*   nidx = (int*)(ws + OFF_NIDX);
    float* stat = ws + OFF_STAT;
    float* sums_d = stat,      *sumsq_d = stat+256,  *scale_d = stat+512,  *shift_d = stat+768;
    float* sums_h = stat+1024, *sumsq_h = stat+1280, *scale_h = stat+1536, *shift_h = stat+1792;
    float* sums_o = stat+2048, *sumsq_o = stat+2304, *scale_o = stat+2560, *shift_o = stat+2816;
    float* out = (float*)d_out;

    hipMemsetAsync(stat, 0, 3*1024*sizeof(float), stream);
    k_copyout<<<(OUT_P1 + BB + 255)/256, 256, 0, stream>>>(p1, o1, out);

    // weight swizzles (hi/lo planes)
    k_swizzle_hl<<<16, 64, 0, stream>>>(W_dense, 128, wts+WDH, wts+WDL);
    k_swizzle_hl<<<32, 64, 0, stream>>>(Wq, 128, wts+WQH, wts+WQL);
    k_swizzle_hl<<<32, 64, 0, stream>>>(Wk, 128, wts+WKH, wts+WKL);
    k_swizzle_hl<<<32, 64, 0, stream>>>(Wv, 128, wts+WVH, wts+WVL);
    k_swizzle_hl<<<32, 64, 0, stream>>>(W1, 128, wts+W1H, wts+W1L);
    k_swizzle_hl<<<32, 64, 0, stream>>>(W2, 128, wts+W2H, wts+W2L);
    k_swizzle_hl<<<96, 64, 0, stream>>>(W_out, 256, wts+WOH, wts+WOL);

    // dense_mlp
    k_gemm_mf<128,64,0><<<M1/64, 256, 0, stream>>>(x1, wts+WDH, wts+WDL, b_dense, tmp, nullptr);
    k_colstats<<<128, 256, 0, stream>>>(tmp, M1, DS, sums_d, sumsq_d);
    k_finalize<<<1, 256, 0, stream>>>(sums_d, sumsq_d, g_dense, bt_dense, M1, DS, scale_d, shift_d);
    k_bnrelu<<<(M1*DS)/256, 256, 0, stream>>>(tmp, scale_d, shift_d, xd, (size_t)M1*DS, DS);

    // interpolation
    k_interp<<<M1, 64, 0, stream>>>(p1, p2, x2, xi);

    // q, k, v projections
    k_gemm_mf<128,128,0><<<M1/64, 256, 0, stream>>>(xd, wts+WQH, wts+WQL, nullptr, qm, nullptr);
    k_gemm_mf<128,128,0><<<M1/64, 256, 0, stream>>>(xi, wts+WKH, wts+WKL, nullptr, km, nullptr);
    k_gemm_mf<128,128,0><<<M1/64, 256, 0, stream>>>(xi, wts+WVH, wts+WVL, nullptr, vm, nullptr);

    // kNN (radix select)
    k_knn_rs<<<M1, 64, 0, stream>>>(p1, nidx);

    // h-GEMM (MFMA, fused BN stats) -> hpre bf16
    k_gemm_h<<<MH/128, 256, 0, stream>>>(qm, km, xd, nidx, wts+W1H, b1, hpre, sums_h, sumsq_h);
    k_finalize<<<1, 256, 0, stream>>>(sums_h, sumsq_h, g1, bt1, MH, DS, scale_h, shift_h);

    // attn (MFMA)
    k_attn2<<<M1/4, 256, 0, stream>>>(hpre, scale_h, shift_h, wts+W2H, vm, xd, nidx, tmp);

    // output mlp
    k_gemm_mf<256,192,2><<<M1/64, 256, 0, stream>>>(tmp, wts+WOH, wts+WOL, b_out, outp, x1);
    k_colstats<<<128, 256, 0, stream>>>(outp, M1, DOUT, sums_o, sumsq_o);
    k_finalize<<<1, 256, 0, stream>>>(sums_o, sumsq_o, g_out, bt_out, M1, DOUT, scale_o, shift_o);
    k_bnrelu<<<(M1*DOUT)/256, 256, 0, stream>>>(outp, scale_o, shift_o, out + OUT_X,
        (size_t)M1*DOUT, DOUT);
}